// Round 16
// baseline (1105.567 us; speedup 1.0000x reference)
//
#include <hip/hip_runtime.h>

// RK4 neural-ODE: f(y) = tanh(y W1 + b1) W2 + b2;  3072 rows x 255 steps.
//
// ROUND 20 == ROUND 19 resubmit (R19 never ran: acquisition timeout).
// THREE ROWS PER WAVE, ONE WAVE PER SIMD, SINGLE PASS.
// Evidence: R16 = 790.8us, occupancy 26% = 2 waves/SIMD resident while the
// problem needs 3 rows/SIMD => 1.5-pass execution with a 33% tail; reg total
// (84 arch + hidden AGPR) stuck in (170,256] across every attribute/pin/
// scalarize experiment (R6/R7/R8/R16). Fix: restructure so neither matters:
//   - 256 blocks x 256 thr = 1 block/CU, 4 waves/CU, 1 wave/SIMD, exactly
//     3072 rows in ONE pass, perfectly balanced.
//   - each wave integrates 3 rows INTERLEAVED: 3 independent dep chains
//     cover FMA latency and the ~120cy LDS h/y round-trips (phase1 of rows
//     B,C issues ~320cy between row A's h-write and h-read).
//   - waves_per_eu(1,1): 512-reg budget, demand ~200 => all-arch-VGPR,
//     no AGPR split possible, no copy tax.
// Issue floor: 3 x 177 slots = 1062 cy/SIMD/eval -> 451us at 100% util.
// Per-row math order IDENTICAL to R16 (scalar fmaf chains, LDS y-broadcast,
// stride-20 h layout, DPP+bpermute combine) => absmax must stay 0.015625.
// Predict: dur 500-600us, VGPR_Count ~180-240 (decisive tell), VALUBusy>=80.
// Refute: VGPR <=100 => weight-remat pathology -> W2-in-LDS next;
//         dur >=750 w/ high VGPR => latency-bound -> revert geometry.

typedef float f2 __attribute__((ext_vector_type(2)));
typedef float f4 __attribute__((ext_vector_type(4)));

// tanh(z) with z pre-scaled by 2*log2(e): tanh = 1 - 2/(2^z + 1)
__device__ __forceinline__ float tanh_scaled(float z) {
  float t = __builtin_amdgcn_exp2f(z);
  return fmaf(-2.0f, __builtin_amdgcn_rcpf(t + 1.0f), 1.0f);
}
// quad_perm xor-1 / xor-2 (VALU-pipe cross-lane)
__device__ __forceinline__ float dpp_xor1(float x) {
  return __int_as_float(__builtin_amdgcn_update_dpp(
      0, __float_as_int(x), 0xB1, 0xF, 0xF, true));  // [1,0,3,2]
}
__device__ __forceinline__ float dpp_xor2(float x) {
  return __int_as_float(__builtin_amdgcn_update_dpp(
      0, __float_as_int(x), 0x4E, 0xF, 0xF, true));  // [2,3,0,1]
}

__global__ void __launch_bounds__(256)
__attribute__((amdgpu_waves_per_eu(1, 1)))
rk4_ode_kernel(const float* __restrict__ fp,   // [3072,32]
               const float* __restrict__ ts,   // [256]
               const float* __restrict__ W1,   // [32,128]
               const float* __restrict__ b1,   // [128]
               const float* __restrict__ W2,   // [128,32]
               const float* __restrict__ b2,   // [32]
               float* __restrict__ out) {      // [3072,256,32]
  // per wave: 3 h buffers (160 fl each, stride-20 chunks) + 3 y buffers (32)
  __shared__ float smem[4 * 576];

  const int tid = threadIdx.x;
  const int wv  = tid >> 6;
  const int p   = tid & 63;
  const int row0 = blockIdx.x * 12 + wv * 3;   // this wave's 3 rows

  const int g  = (p & 3) | ((p >> 5) << 2);    // j-group: lane bits {0,1,5}
  const int j0 = g << 4;                       // 16 j's per group
  const int d0 = p & 0x1C;                     // outputs d0|m, m=0..3

  const float C = 2.885390081777926814f;       // 2*log2(e) folded into W1/b1

  // ---- W1: lane p produces h_{2p}, h_{2p+1}; scalar col-pair regs ----
  float w1x[32], w1y[32];
  const float2* W1v = reinterpret_cast<const float2*>(W1);
#pragma unroll
  for (int dd = 0; dd < 32; ++dd) {
    const float2 t_ = W1v[dd * 64 + p];
    w1x[dd] = t_.x * C; w1y[dd] = t_.y * C;
  }
  const float2 b1t = reinterpret_cast<const float2*>(b1)[p];
  const float b1x = b1t.x * C, b1y = b1t.y * C;

  // ---- W2: rows [j0, j0+16) for 4 outputs d0|m, scalar j-pair regs ----
  float w2a[4][8], w2b[4][8];
#pragma unroll
  for (int m = 0; m < 4; ++m)
#pragma unroll
    for (int i = 0; i < 8; ++i) {
      w2a[m][i] = W2[(j0 + 2 * i)     * 32 + (d0 | m)];
      w2b[m][i] = W2[(j0 + 2 * i + 1) * 32 + (d0 | m)];
    }
  const float b2l = b2[p & 31];

  // ---- per-row RK4 state: lane p holds dim d = p&31 for 3 rows ----
  float y0[3], ycur[3], kacc[3];

  float* wb  = &smem[wv * 576];                 // wave base
  float* hwr = wb + 20 * (p >> 3) + 2 * (p & 7); // h write addr (+ r*160)
  const int pairaddr = (p ^ 32) << 2;

#pragma unroll
  for (int r = 0; r < 3; ++r) {
    y0[r]   = fp[(row0 + r) * 32 + (p & 31)];
    ycur[r] = y0[r];
    kacc[r] = 0.0f;
    if (p < 32) out[(size_t)(row0 + r) * 8192 + p] = y0[r];
    // seed y broadcast (lanes p and p^32 write same value: free 2-way dup)
    wb[480 + r * 32 + (p & 31)] = ycur[r];
  }
  __builtin_amdgcn_wave_barrier();

  for (int t = 0; t < 255; ++t) {
    const float dt = ts[t + 1] - ts[t];
#pragma unroll
    for (int st = 0; st < 4; ++st) {
      // ---- phase 1, rows 0..2 interleaved: z = C*(b1 + y.W1) ----
#pragma unroll
      for (int r = 0; r < 3; ++r) {
        const f4* yrd = reinterpret_cast<const f4*>(wb + 480 + r * 32);
        float aex = b1x, aox = 0.0f, aey = b1y, aoy = 0.0f;
#pragma unroll
        for (int q = 0; q < 8; ++q) {
          const f4 yv = yrd[q];
          aex = fmaf(yv.x, w1x[4 * q + 0], aex);
          aey = fmaf(yv.x, w1y[4 * q + 0], aey);
          aox = fmaf(yv.y, w1x[4 * q + 1], aox);
          aoy = fmaf(yv.y, w1y[4 * q + 1], aoy);
          aex = fmaf(yv.z, w1x[4 * q + 2], aex);
          aey = fmaf(yv.z, w1y[4 * q + 2], aey);
          aox = fmaf(yv.w, w1x[4 * q + 3], aox);
          aoy = fmaf(yv.w, w1y[4 * q + 3], aoy);
        }
        const float ax = aex + aox;
        const float ay = aey + aoy;
        *reinterpret_cast<f2*>(hwr + r * 160) =
            (f2){tanh_scaled(ax), tanh_scaled(ay)};
      }
      __builtin_amdgcn_wave_barrier();          // h writes before h reads

      // ---- phase 2 + combine + RK4, rows 0..2 ----
#pragma unroll
      for (int r = 0; r < 3; ++r) {
        const f4* hrd = reinterpret_cast<const f4*>(wb + r * 160 + 20 * g);
        float accx[4] = {0, 0, 0, 0}, accy[4] = {0, 0, 0, 0};
        {
          const f4 r_0 = hrd[0], r_1 = hrd[1];
#pragma unroll
          for (int m = 0; m < 4; ++m) {
            accx[m] = fmaf(r_0.x, w2a[m][0], accx[m]);
            accy[m] = fmaf(r_0.y, w2b[m][0], accy[m]);
            accx[m] = fmaf(r_0.z, w2a[m][1], accx[m]);
            accy[m] = fmaf(r_0.w, w2b[m][1], accy[m]);
            accx[m] = fmaf(r_1.x, w2a[m][2], accx[m]);
            accy[m] = fmaf(r_1.y, w2b[m][2], accy[m]);
            accx[m] = fmaf(r_1.z, w2a[m][3], accx[m]);
            accy[m] = fmaf(r_1.w, w2b[m][3], accy[m]);
          }
          const f4 r_2 = hrd[2], r_3 = hrd[3];
#pragma unroll
          for (int m = 0; m < 4; ++m) {
            accx[m] = fmaf(r_2.x, w2a[m][4], accx[m]);
            accy[m] = fmaf(r_2.y, w2b[m][4], accy[m]);
            accx[m] = fmaf(r_2.z, w2a[m][5], accx[m]);
            accy[m] = fmaf(r_2.w, w2b[m][5], accy[m]);
            accx[m] = fmaf(r_3.x, w2a[m][6], accx[m]);
            accy[m] = fmaf(r_3.y, w2b[m][6], accy[m]);
            accx[m] = fmaf(r_3.z, w2a[m][7], accx[m]);
            accy[m] = fmaf(r_3.w, w2b[m][7], accy[m]);
          }
        }

        // combine group partials: ^1,^2 via DPP (VALU), select, then ^32
        float k0 = accx[0] + accy[0], k1 = accx[1] + accy[1];
        float k2 = accx[2] + accy[2], k3 = accx[3] + accy[3];
        k0 += dpp_xor1(k0); k1 += dpp_xor1(k1);
        k2 += dpp_xor1(k2); k3 += dpp_xor1(k3);
        k0 += dpp_xor2(k0); k1 += dpp_xor2(k1);
        k2 += dpp_xor2(k2); k3 += dpp_xor2(k3);
        const float s01 = (p & 1) ? k1 : k0;
        const float s23 = (p & 1) ? k3 : k2;
        const float ks  = (p & 2) ? s23 : s01;   // my output's quad partial
        const float k = ks + b2l + __int_as_float(
            __builtin_amdgcn_ds_bpermute(pairaddr, __float_as_int(ks)));

        // RK4 stage combination (st is compile-time)
        if (st == 0) {
          kacc[r] = k;                      ycur[r] = fmaf(0.5f * dt, k, y0[r]);
        } else if (st == 1) {
          kacc[r] = fmaf(2.0f, k, kacc[r]); ycur[r] = fmaf(0.5f * dt, k, y0[r]);
        } else if (st == 2) {
          kacc[r] = fmaf(2.0f, k, kacc[r]); ycur[r] = fmaf(dt, k, y0[r]);
        } else {
          kacc[r] = kacc[r] + k;
          y0[r]   = fmaf(dt * (1.0f / 6.0f), kacc[r], y0[r]);
          ycur[r] = y0[r];
        }
        // publish y for next stage's broadcast (2-way same-addr dup: free)
        wb[480 + r * 32 + (p & 31)] = ycur[r];
      }
      __builtin_amdgcn_wave_barrier();          // y/h consumed before rewrite
    }
#pragma unroll
    for (int r = 0; r < 3; ++r)
      if (p < 32) out[(size_t)(row0 + r) * 8192 + (t + 1) * 32 + p] = y0[r];
  }
}

extern "C" void kernel_launch(void* const* d_in, const int* in_sizes, int n_in,
                              void* d_out, int out_size, void* d_ws, size_t ws_size,
                              hipStream_t stream) {
  const float* fp = (const float*)d_in[0];   // first_point [3,1024,32]
  const float* ts = (const float*)d_in[1];   // time_steps [256]
  const float* W1 = (const float*)d_in[2];   // [32,128]
  const float* b1 = (const float*)d_in[3];   // [128]
  const float* W2 = (const float*)d_in[4];   // [128,32]
  const float* b2 = (const float*)d_in[5];   // [32]
  float* out = (float*)d_out;                // [3,1024,256,32]

  rk4_ode_kernel<<<256, 256, 0, stream>>>(fp, ts, W1, b1, W2, b2, out);
}

// Round 21
// 769.090 us; speedup vs baseline: 1.4375x; 1.4375x over previous
//
#include <hip/hip_runtime.h>

// RK4 neural-ODE: f(y) = tanh(y W1 + b1) W2 + b2;  3072 rows x 255 steps.
// One wave per row, wave-synchronous. 768x256, waves_per_eu(3,3).
//
// ROUND 25 == ROUND 21/22/23/24 resubmit (none ran: acquisition timeouts).
// LIVE-RANGE SQUEEZE -> fit 3 waves/SIMD.
// Evidence: R19 (1 wave/SIMD, 3-row ILP) = 1105us, VALUBusy 54% -> per-wave
// serial stalls (~400cy/stage: y-read 120 + h roundtrip + bpermute 120) can
// only be filled by OTHER WAVES (TLP), not own ILP. R16 (best, 790.8us) had
// only 2/3 needed waves resident: total regs (84 arch + ~112 AGPR ~= 196) in
// (170,256]. HW occupancy counts arch+AGPR TOTAL -- don't fight the split,
// shrink the total. Biggest lever: compiler hoists all 8 y-broadcast b128s
// (32 VGPRs) + h-reads into one big live set. This round: split phase1 into
// 2x4-b128 halves and phase2 into 2x2-b128 halves, each second half FENCED
// with wave_barrier so loads cannot hoist -> ~16-24 fewer live regs ->
// total <= 170 -> 3 waves/SIMD, single pass, stalls covered by TLP.
// FMA order byte-identical to R16 => absmax must stay 0.015625.
// Predict: Occupancy 26->35-38% (decisive tell), dur 550-660us, VALUBusy
// 85-95%. Partial refute: occupancy ~26% -> total still >170 -> dur ~800.
// Revert: dur > 900.

typedef float f2 __attribute__((ext_vector_type(2)));
typedef float f4 __attribute__((ext_vector_type(4)));

// tanh(z) with z pre-scaled by 2*log2(e): tanh = 1 - 2/(2^z + 1)
__device__ __forceinline__ float tanh_scaled(float z) {
  float t = __builtin_amdgcn_exp2f(z);
  return fmaf(-2.0f, __builtin_amdgcn_rcpf(t + 1.0f), 1.0f);
}
// quad_perm xor-1 / xor-2 (VALU-pipe cross-lane)
__device__ __forceinline__ float dpp_xor1(float x) {
  return __int_as_float(__builtin_amdgcn_update_dpp(
      0, __float_as_int(x), 0xB1, 0xF, 0xF, true));  // [1,0,3,2]
}
__device__ __forceinline__ float dpp_xor2(float x) {
  return __int_as_float(__builtin_amdgcn_update_dpp(
      0, __float_as_int(x), 0x4E, 0xF, 0xF, true));  // [2,3,0,1]
}

#define REP32(X) \
  X(0) X(1) X(2) X(3) X(4) X(5) X(6) X(7) X(8) X(9) X(10) X(11) X(12) X(13) \
  X(14) X(15) X(16) X(17) X(18) X(19) X(20) X(21) X(22) X(23) X(24) X(25)   \
  X(26) X(27) X(28) X(29) X(30) X(31)

__global__ void __launch_bounds__(256)
__attribute__((amdgpu_waves_per_eu(3, 3)))
rk4_ode_kernel(const float* __restrict__ fp,   // [3072,32]
               const float* __restrict__ ts,   // [256]
               const float* __restrict__ W1,   // [32,128]
               const float* __restrict__ b1,   // [128]
               const float* __restrict__ W2,   // [128,32]
               const float* __restrict__ b2,   // [32]
               float* __restrict__ out) {      // [3072,256,32]
  // per-wave: h buffer (8 chunks of 16 floats at stride 20, bank stagger)
  // + y broadcast buffer (32 floats)
  __shared__ float smem[4 * 160 + 4 * 32];

  const int tid = threadIdx.x;
  const int wv  = tid >> 6;
  const int p   = tid & 63;
  const int row = blockIdx.x * 4 + wv;

  const int g  = (p & 3) | ((p >> 5) << 2);   // j-group: lane bits {0,1,5}
  const int j0 = g << 4;                      // 16 j's per group
  const int d0 = p & 0x1C;                    // outputs d0|m, m=0..3

  const float C = 2.885390081777926814f;      // 2*log2(e) folded into W1/b1

  // ---- W1: lane p produces h_{2p}, h_{2p+1}; SCALAR col-pair regs ----
  const float2* W1v = reinterpret_cast<const float2*>(W1);
#define LOADW1(dd) float w1x_##dd, w1y_##dd; \
  { const float2 t_ = W1v[dd * 64 + p]; w1x_##dd = t_.x * C; w1y_##dd = t_.y * C; }
  REP32(LOADW1)
#undef LOADW1
  const float2 b1t = reinterpret_cast<const float2*>(b1)[p];
  const float b1x = b1t.x * C, b1y = b1t.y * C;

  // ---- W2: rows [j0, j0+16) for 4 outputs d0|m, SCALAR j-pair regs ----
#define LW2(m) \
  const float w2a_##m##_0 = W2[(j0 + 0)  * 32 + (d0 | m)], w2b_##m##_0 = W2[(j0 + 1)  * 32 + (d0 | m)]; \
  const float w2a_##m##_1 = W2[(j0 + 2)  * 32 + (d0 | m)], w2b_##m##_1 = W2[(j0 + 3)  * 32 + (d0 | m)]; \
  const float w2a_##m##_2 = W2[(j0 + 4)  * 32 + (d0 | m)], w2b_##m##_2 = W2[(j0 + 5)  * 32 + (d0 | m)]; \
  const float w2a_##m##_3 = W2[(j0 + 6)  * 32 + (d0 | m)], w2b_##m##_3 = W2[(j0 + 7)  * 32 + (d0 | m)]; \
  const float w2a_##m##_4 = W2[(j0 + 8)  * 32 + (d0 | m)], w2b_##m##_4 = W2[(j0 + 9)  * 32 + (d0 | m)]; \
  const float w2a_##m##_5 = W2[(j0 + 10) * 32 + (d0 | m)], w2b_##m##_5 = W2[(j0 + 11) * 32 + (d0 | m)]; \
  const float w2a_##m##_6 = W2[(j0 + 12) * 32 + (d0 | m)], w2b_##m##_6 = W2[(j0 + 13) * 32 + (d0 | m)]; \
  const float w2a_##m##_7 = W2[(j0 + 14) * 32 + (d0 | m)], w2b_##m##_7 = W2[(j0 + 15) * 32 + (d0 | m)];
  LW2(0) LW2(1) LW2(2) LW2(3)
#undef LW2
  const float b2l = b2[p & 31];

  // ---- RK4 state: lane p holds dim d = p&31 (valid on all 64 lanes) ----
  float y0   = fp[row * 32 + (p & 31)];
  float ycur = y0;
  float kacc = 0.0f;

  float* outrow = out + (size_t)row * (256 * 32);
  if (p < 32) outrow[p] = y0;

  // h LDS addressing: h_j stored at float index 20*(j>>4) + (j&15)
  float* hwbase = &smem[wv * 160];
  float* hwr    = hwbase + 20 * (p >> 3) + 2 * (p & 7);   // write f2 (j=2p,2p+1)
  const f4* hrd = reinterpret_cast<const f4*>(hwbase + 20 * g); // 4x b128 reads
  // y broadcast buffer
  float* ybase  = &smem[640 + wv * 32];
  const f4* yrd = reinterpret_cast<const f4*>(ybase);
  const int pairaddr = (p ^ 32) << 2;

  // seed y broadcast (lanes p and p^32 write the same value: free 2-way dup)
  ybase[p & 31] = ycur;
  __builtin_amdgcn_wave_barrier();

  for (int t = 0; t < 255; ++t) {
    const float dt = ts[t + 1] - ts[t];
#pragma unroll
    for (int st = 0; st < 4; ++st) {
      // ---- phase 1: z = C*(b1 + y.W1) for cols 2p,2p+1 ----
      // Half A: y floats 0..15 (4 b128), consume, FENCE, half B: 16..31.
      // Fence stops the compiler hoisting half-B loads -> live yv = 16 not 32.
      float aex = b1x, aox = 0.0f, aey = b1y, aoy = 0.0f;
#define P1E(s, dd) { aex = fmaf((s), w1x_##dd, aex); aey = fmaf((s), w1y_##dd, aey); }
#define P1O(s, dd) { aox = fmaf((s), w1x_##dd, aox); aoy = fmaf((s), w1y_##dd, aoy); }
      {
        const f4 yv_0 = yrd[0]; const f4 yv_1 = yrd[1];
        const f4 yv_2 = yrd[2]; const f4 yv_3 = yrd[3];
        P1E(yv_0.x, 0)  P1O(yv_0.y, 1)  P1E(yv_0.z, 2)  P1O(yv_0.w, 3)
        P1E(yv_1.x, 4)  P1O(yv_1.y, 5)  P1E(yv_1.z, 6)  P1O(yv_1.w, 7)
        P1E(yv_2.x, 8)  P1O(yv_2.y, 9)  P1E(yv_2.z, 10) P1O(yv_2.w, 11)
        P1E(yv_3.x, 12) P1O(yv_3.y, 13) P1E(yv_3.z, 14) P1O(yv_3.w, 15)
      }
      __builtin_amdgcn_wave_barrier();          // live-range fence (half B)
      {
        const f4 yv_4 = yrd[4]; const f4 yv_5 = yrd[5];
        const f4 yv_6 = yrd[6]; const f4 yv_7 = yrd[7];
        P1E(yv_4.x, 16) P1O(yv_4.y, 17) P1E(yv_4.z, 18) P1O(yv_4.w, 19)
        P1E(yv_5.x, 20) P1O(yv_5.y, 21) P1E(yv_5.z, 22) P1O(yv_5.w, 23)
        P1E(yv_6.x, 24) P1O(yv_6.y, 25) P1E(yv_6.z, 26) P1O(yv_6.w, 27)
        P1E(yv_7.x, 28) P1O(yv_7.y, 29) P1E(yv_7.z, 30) P1O(yv_7.w, 31)
      }
#undef P1E
#undef P1O
      const float ax = aex + aox;
      const float ay = aey + aoy;
      *reinterpret_cast<f2*>(hwr) = (f2){tanh_scaled(ax), tanh_scaled(ay)};
      __builtin_amdgcn_wave_barrier();          // h write before h reads

      // ---- phase 2: 16 h-floats for my j-group vs 4 output columns ----
      float accx0 = 0, accy0 = 0, accx1 = 0, accy1 = 0;
      float accx2 = 0, accy2 = 0, accx3 = 0, accy3 = 0;
      {
        const f4 r_0 = hrd[0], r_1 = hrd[1];
#define ACCA(m) accx##m = fmaf(r_0.x, w2a_##m##_0, accx##m); \
                accy##m = fmaf(r_0.y, w2b_##m##_0, accy##m); \
                accx##m = fmaf(r_0.z, w2a_##m##_1, accx##m); \
                accy##m = fmaf(r_0.w, w2b_##m##_1, accy##m); \
                accx##m = fmaf(r_1.x, w2a_##m##_2, accx##m); \
                accy##m = fmaf(r_1.y, w2b_##m##_2, accy##m); \
                accx##m = fmaf(r_1.z, w2a_##m##_3, accx##m); \
                accy##m = fmaf(r_1.w, w2b_##m##_3, accy##m);
        ACCA(0) ACCA(1) ACCA(2) ACCA(3)
#undef ACCA
      }
      __builtin_amdgcn_wave_barrier();          // live-range fence (r_2,r_3)
      {
        const f4 r_2 = hrd[2], r_3 = hrd[3];
#define ACCB(m) accx##m = fmaf(r_2.x, w2a_##m##_4, accx##m); \
                accy##m = fmaf(r_2.y, w2b_##m##_4, accy##m); \
                accx##m = fmaf(r_2.z, w2a_##m##_5, accx##m); \
                accy##m = fmaf(r_2.w, w2b_##m##_5, accy##m); \
                accx##m = fmaf(r_3.x, w2a_##m##_6, accx##m); \
                accy##m = fmaf(r_3.y, w2b_##m##_6, accy##m); \
                accx##m = fmaf(r_3.z, w2a_##m##_7, accx##m); \
                accy##m = fmaf(r_3.w, w2b_##m##_7, accy##m);
        ACCB(0) ACCB(1) ACCB(2) ACCB(3)
#undef ACCB
      }
      __builtin_amdgcn_wave_barrier();          // h reads before next h write

      // ---- combine group partials: ^1,^2 via DPP (VALU), select, then ^32 ----
      float k0 = accx0 + accy0, k1 = accx1 + accy1;
      float k2 = accx2 + accy2, k3 = accx3 + accy3;
      k0 += dpp_xor1(k0); k1 += dpp_xor1(k1); k2 += dpp_xor1(k2); k3 += dpp_xor1(k3);
      k0 += dpp_xor2(k0); k1 += dpp_xor2(k1); k2 += dpp_xor2(k2); k3 += dpp_xor2(k3);
      const float s01 = (p & 1) ? k1 : k0;
      const float s23 = (p & 1) ? k3 : k2;
      const float ks  = (p & 2) ? s23 : s01;    // my output's quad partial
      const float k = ks + b2l + __int_as_float(
          __builtin_amdgcn_ds_bpermute(pairaddr, __float_as_int(ks)));

      // ---- RK4 stage combination ----
      if (st == 0) {
        kacc = k;                   ycur = fmaf(0.5f * dt, k, y0);
      } else if (st == 1) {
        kacc = fmaf(2.0f, k, kacc); ycur = fmaf(0.5f * dt, k, y0);
      } else if (st == 2) {
        kacc = fmaf(2.0f, k, kacc); ycur = fmaf(dt, k, y0);
      } else {
        kacc = kacc + k;
        y0   = fmaf(dt * (1.0f / 6.0f), kacc, y0);
        ycur = y0;
      }

      // publish y for next stage's broadcast (2-way same-addr dup: free)
      ybase[p & 31] = ycur;
      __builtin_amdgcn_wave_barrier();          // y write before next y reads
    }
    if (p < 32) outrow[(t + 1) * 32 + p] = y0;
  }
}

extern "C" void kernel_launch(void* const* d_in, const int* in_sizes, int n_in,
                              void* d_out, int out_size, void* d_ws, size_t ws_size,
                              hipStream_t stream) {
  const float* fp = (const float*)d_in[0];   // first_point [3,1024,32]
  const float* ts = (const float*)d_in[1];   // time_steps [256]
  const float* W1 = (const float*)d_in[2];   // [32,128]
  const float* b1 = (const float*)d_in[3];   // [128]
  const float* W2 = (const float*)d_in[4];   // [128,32]
  const float* b2 = (const float*)d_in[5];   // [32]
  float* out = (float*)d_out;                // [3,1024,256,32]

  rk4_ode_kernel<<<768, 256, 0, stream>>>(fp, ts, W1, b1, W2, b2, out);
}